// Round 6
// baseline (113.388 us; speedup 1.0000x reference)
//
#include <hip/hip_runtime.h>
#include <math.h>

// NetVLAD: B=64, N=1024, D=512, K=64, G=16 (C=80)
#define BB 64
#define NN 1024
#define DD 512
#define KK 64
#define CC 80

typedef __attribute__((ext_vector_type(8))) short short8;  // 8 bf16 (4 VGPRs)
typedef __attribute__((ext_vector_type(4))) float f32x4;   // MFMA accumulator

union U16x8 { uint4 u; short8 s; };

// Split fp32 -> bf16 hi (truncated) + bf16 lo (truncated remainder).
// Products hi*hi + lo*hi + hi*lo give ~2^-16 relative error.
__device__ __forceinline__ void cvt_hilo8(const float* f, short8& hi, short8& lo) {
#pragma unroll
    for (int j = 0; j < 8; ++j) {
        unsigned u = __float_as_uint(f[j]);
        unsigned uh = u & 0xFFFF0000u;
        float fl = f[j] - __uint_as_float(uh);
        hi[j] = (short)(uh >> 16);
        lo[j] = (short)(__float_as_uint(fl) >> 16);
    }
}

// ---------------------------------------------------------------------------
// K0: pre-swizzle clusters (512x80 fp32) into per-lane MFMA B-frag layout,
// bf16 hi/lo. Entry (ks,q,l,dw): q = tile*2+part; c = tile*16+(l&15);
// d = ks*32+(l>>4)*8+dw*2+{0,1}. 40960 dwords = 160KB.
// ---------------------------------------------------------------------------
__global__ __launch_bounds__(256) void k_prep(
    const float* __restrict__ clusters, unsigned int* __restrict__ bfrag)
{
    int i = blockIdx.x * 256 + threadIdx.x;
    if (i >= 16 * 10 * 64 * 4) return;
    int dw = i & 3;
    int l = (i >> 2) & 63;
    int rest = i >> 8;           // 0..159
    int q = rest % 10;
    int ks = rest / 10;
    int tile = q >> 1, part = q & 1;
    int c = tile * 16 + (l & 15);
    int dbase = ks * 32 + (l >> 4) * 8 + dw * 2;
    unsigned outw = 0;
#pragma unroll
    for (int e = 0; e < 2; ++e) {
        float v = clusters[(size_t)(dbase + e) * CC + c];
        unsigned u = __float_as_uint(v);
        unsigned uh = u & 0xFFFF0000u;
        unsigned h;
        if (part == 0) h = uh >> 16;
        else {
            float fl = v - __uint_as_float(uh);
            h = __float_as_uint(fl) >> 16;
        }
        outw |= h << (16 * e);
    }
    bfrag[i] = outw;
}

// ---------------------------------------------------------------------------
// K1: scores = x @ clusters via split-bf16 MFMA, BN, softmax(80), first-64
// -> assign + per-block column sums. Block = 64 rows, 4 waves.
// DOUBLE-BUFFERED LDS, ONE barrier per K-chunk, issue-early reg prefetch
// (reg loads survive barriers; deliberately no global_load_lds whose
// pre-barrier vmcnt(0) drain would kill the pipeline). Loop unrolled x2
// with named reg sets A/B so buffer indices are compile-time.
// Steady state, iter ks: compute(buf[ks&1]) ; ds_write buf[(ks+1)&1] <-
// regs(ks+1) ; issue loads(ks+2) ; barrier.
// C/D layout: col = lane&15 (cluster), row = (lane>>4)*4 + reg (x-row).
// ---------------------------------------------------------------------------
__global__ __launch_bounds__(256, 3) void k_assign_mfma(
    const float* __restrict__ x,           // (B*N, D)
    const unsigned int* __restrict__ bfrag,
    const float* __restrict__ rmean,
    const float* __restrict__ rvar,
    float* __restrict__ assign,            // (B*N, K)
    float* __restrict__ asum_part)         // (1024, K)
{
    __shared__ float4 xs3[2][4][64][3];   // 24KB ([3] pad: frag reads 2/bank)
    __shared__ uint4 bfu[2][640];         // 20KB (lane-linear, conflict-free)
    __shared__ float colp[4][64];
    __shared__ float bnm[CC], bns[CC];

    const int t = threadIdx.x;
    const int w = t >> 6;       // wave 0..3
    const int l = t & 63;       // lane
    const int row0 = blockIdx.x * 64;

    if (t < CC) {
        bnm[t] = rmean[t];
        bns[t] = rsqrtf(rvar[t] + 1e-5f);
    }

    f32x4 acc[5];
#pragma unroll
    for (int nt = 0; nt < 5; ++nt)
#pragma unroll
        for (int r = 0; r < 4; ++r) acc[nt][r] = 0.f;

    // staging roles (per thread): rows rA, rA+32 at d-quad dq
    const int rA = t >> 3;        // 0..31
    const int dq = t & 7;         // 0..7
    const int g = dq >> 1, half = dq & 1;
    const float* xg = x + (size_t)(row0 + rA) * DD + dq * 4;
    const uint4* gb0 = (const uint4*)bfrag;

    // fragment-read roles
    const int frow = w * 16 + (l & 15);
    const int fg = l >> 4;

    float4 pvA0, pvA1, pvB0, pvB1;
    uint4 pbA0, pbA1, pbA2, pbB0, pbB1, pbB2;

#define LOAD_SET(S, ksv)                                            \
    do {                                                            \
        const float* xn = xg + (ksv) * 32;                          \
        pv##S##0 = *(const float4*)(xn);                            \
        pv##S##1 = *(const float4*)(xn + 32 * DD);                  \
        const uint4* gb = gb0 + (size_t)(ksv) * 640;                \
        pb##S##0 = gb[t];                                           \
        pb##S##1 = gb[t + 256];                                     \
        if (t < 128) pb##S##2 = gb[t + 512];                        \
    } while (0)

#define STAGE_SET(S, bi)                                            \
    do {                                                            \
        xs3[bi][g][rA][half] = pv##S##0;                            \
        xs3[bi][g][rA + 32][half] = pv##S##1;                       \
        bfu[bi][t] = pb##S##0;                                      \
        bfu[bi][t + 256] = pb##S##1;                                \
        if (t < 128) bfu[bi][t + 512] = pb##S##2;                   \
    } while (0)

#define COMPUTE(bi)                                                 \
    do {                                                            \
        float4 a0 = xs3[bi][fg][frow][0];                           \
        float4 a1 = xs3[bi][fg][frow][1];                           \
        float ftmp[8] = {a0.x, a0.y, a0.z, a0.w,                    \
                         a1.x, a1.y, a1.z, a1.w};                   \
        short8 ah, al;                                              \
        cvt_hilo8(ftmp, ah, al);                                    \
        _Pragma("unroll")                                           \
        for (int nt = 0; nt < 5; ++nt) {                            \
            U16x8 uh, ul;                                           \
            uh.u = bfu[bi][(nt * 2 + 0) * 64 + l];                  \
            ul.u = bfu[bi][(nt * 2 + 1) * 64 + l];                  \
            acc[nt] = __builtin_amdgcn_mfma_f32_16x16x32_bf16(      \
                ah, uh.s, acc[nt], 0, 0, 0);                        \
            acc[nt] = __builtin_amdgcn_mfma_f32_16x16x32_bf16(      \
                al, uh.s, acc[nt], 0, 0, 0);                        \
            acc[nt] = __builtin_amdgcn_mfma_f32_16x16x32_bf16(      \
                ah, ul.s, acc[nt], 0, 0, 0);                        \
        }                                                           \
    } while (0)

    // prologue: buf0 <- ks0; loads for ks1 in flight
    LOAD_SET(A, 0);
    STAGE_SET(A, 0);            // compiler inserts the vmcnt wait for set A
    LOAD_SET(B, 1);
    __syncthreads();

    for (int ks2 = 0; ks2 < 8; ++ks2) {
        const int ks = ks2 * 2;
        // even half: data ks in buf0; stage ks+1 -> buf1; issue ks+2 -> A
        COMPUTE(0);
        STAGE_SET(B, 1);                      // waits vmcnt for set B only
        if (ks2 < 7) LOAD_SET(A, ks + 2);
        __syncthreads();
        // odd half: data ks+1 in buf1; stage ks+2 -> buf0; issue ks+3 -> B
        COMPUTE(1);
        if (ks2 < 7) {
            STAGE_SET(A, 0);
            if (ks + 3 < 16) LOAD_SET(B, ks + 3);
            __syncthreads();
        }
    }

    // BN + softmax per row, fully in-register (cols of a row in 16-lane group)
    float a[4][4];
#pragma unroll
    for (int r = 0; r < 4; ++r) {
        float sc[5];
#pragma unroll
        for (int nt = 0; nt < 5; ++nt) {
            int c = nt * 16 + (l & 15);
            sc[nt] = (acc[nt][r] - bnm[c]) * bns[c];
        }
        float m = sc[0];
#pragma unroll
        for (int nt = 1; nt < 5; ++nt) m = fmaxf(m, sc[nt]);
        m = fmaxf(m, __shfl_xor(m, 1));
        m = fmaxf(m, __shfl_xor(m, 2));
        m = fmaxf(m, __shfl_xor(m, 4));
        m = fmaxf(m, __shfl_xor(m, 8));
        float p[5], sum = 0.f;
#pragma unroll
        for (int nt = 0; nt < 5; ++nt) { p[nt] = __expf(sc[nt] - m); sum += p[nt]; }
        sum += __shfl_xor(sum, 1);
        sum += __shfl_xor(sum, 2);
        sum += __shfl_xor(sum, 4);
        sum += __shfl_xor(sum, 8);
        float rinv = 1.f / sum;
#pragma unroll
        for (int nt = 0; nt < 4; ++nt) a[nt][r] = p[nt] * rinv;
    }

    // direct global stores: per (nt,r) instr = 4 segments of 64B
    const int rbase = row0 + w * 16 + (l >> 4) * 4;
    const int cbase = l & 15;
#pragma unroll
    for (int nt = 0; nt < 4; ++nt)
#pragma unroll
        for (int r = 0; r < 4; ++r)
            assign[(size_t)(rbase + r) * KK + nt * 16 + cbase] = a[nt][r];

    // per-wave column sums -> cross-wave reduce via tiny LDS
#pragma unroll
    for (int nt = 0; nt < 4; ++nt) {
        float cs = a[nt][0] + a[nt][1] + a[nt][2] + a[nt][3];
        cs += __shfl_xor(cs, 16);
        cs += __shfl_xor(cs, 32);
        if (l < 16) colp[w][nt * 16 + l] = cs;
    }
    __syncthreads();
    if (t < 64) {
        asum_part[(size_t)blockIdx.x * KK + t] =
            colp[0][t] + colp[1][t] + colp[2][t] + colp[3][t];
    }
#undef LOAD_SET
#undef STAGE_SET
#undef COMPUTE
}

// ---------------------------------------------------------------------------
// K1b: a_sum[b,k] = sum of 16 row-tile partials
// ---------------------------------------------------------------------------
__global__ __launch_bounds__(256) void k_asum_reduce(
    const float* __restrict__ asum_part, float* __restrict__ a_sum)
{
    int i = blockIdx.x * 256 + threadIdx.x;   // 4096 = B*K
    if (i >= BB * KK) return;
    int b = i >> 6, k = i & 63;
    float s = 0.f;
#pragma unroll
    for (int tile = 0; tile < 16; ++tile)
        s += asum_part[(size_t)(b * 16 + tile) * KK + k];
    a_sum[i] = s;
}

// ---------------------------------------------------------------------------
// K2a: partial vlad GEMM over an N-chunk of 256.
// Block = (b, d-tile of 128, n-chunk of 4). 1024 blocks, 256 threads.
// ---------------------------------------------------------------------------
__global__ __launch_bounds__(256) void k_vlad_part(
    const float* __restrict__ x,       // (B*N, D)
    const float* __restrict__ assign,  // (B*N, K)
    float* __restrict__ part)          // (1024, 64*128)
{
    __shared__ float as[32][64];
    __shared__ float xs[32][128];

    const int t = threadIdx.x;
    const int b  = blockIdx.x >> 4;
    const int dt = (blockIdx.x >> 2) & 3;
    const int nc = blockIdx.x & 3;
    const int d0 = dt * 128;

    const int tx = t & 31;   // d cols tx*4..+3
    const int ty = t >> 5;   // 0..7 -> k rows ty*8..+7

    float acc[8][4];
#pragma unroll
    for (int i = 0; i < 8; ++i)
#pragma unroll
        for (int j = 0; j < 4; ++j) acc[i][j] = 0.f;

    const size_t xbase = (size_t)b * NN * DD + d0;
    const size_t abase = (size_t)b * NN * KK;
    const int nbeg = nc * 256;

    for (int n0 = nbeg; n0 < nbeg + 256; n0 += 32) {
        __syncthreads();
#pragma unroll
        for (int i = 0; i < 2; ++i) {
            int f = t + i * 256;
            int n = f >> 4, kq = f & 15;
            *(float4*)&as[n][kq * 4] =
                *(const float4*)(assign + abase + (size_t)(n0 + n) * KK + kq * 4);
        }
#pragma unroll
        for (int i = 0; i < 4; ++i) {
            int f = t + i * 256;
            int n = f >> 5, dq = f & 31;
            *(float4*)&xs[n][dq * 4] =
                *(const float4*)(x + xbase + (size_t)(n0 + n) * DD + dq * 4);
        }
        __syncthreads();
#pragma unroll 4
        for (int n = 0; n < 32; ++n) {
            float4 a0 = *(const float4*)&as[n][ty * 8];
            float4 a1 = *(const float4*)&as[n][ty * 8 + 4];
            float4 bv = *(const float4*)&xs[n][tx * 4];
            float a[8] = {a0.x, a0.y, a0.z, a0.w, a1.x, a1.y, a1.z, a1.w};
            float bb[4] = {bv.x, bv.y, bv.z, bv.w};
#pragma unroll
            for (int i = 0; i < 8; ++i)
#pragma unroll
                for (int j = 0; j < 4; ++j)
                    acc[i][j] = fmaf(a[i], bb[j], acc[i][j]);
        }
    }
    float* p = part + (size_t)blockIdx.x * (KK * 128);
#pragma unroll
    for (int i = 0; i < 8; ++i)
        *(float4*)(p + (size_t)(ty * 8 + i) * 128 + tx * 4) =
            make_float4(acc[i][0], acc[i][1], acc[i][2], acc[i][3]);
}

// ---------------------------------------------------------------------------
// K2b: reduce 4 N-chunk partials, subtract a_sum*c2, intra-norm over k,
//      staged coalesced write, global-sumsq partial. 256 blocks (b, dtile).
// ---------------------------------------------------------------------------
__global__ __launch_bounds__(256) void k_vlad_fin(
    const float* __restrict__ part,    // (1024, 64*128)
    const float* __restrict__ a_sum,   // (B, K)
    const float* __restrict__ c2,      // (K, D)
    float* __restrict__ out,           // (B, D*K)
    float* __restrict__ gsum_part)     // (B*4)
{
    __shared__ float red[8][128];
    __shared__ float sc[128];
    __shared__ float ot[128][65];

    const int t = threadIdx.x;
    const int b = blockIdx.x >> 2;
    const int dt = blockIdx.x & 3;
    const int d0 = dt * 128;

    const int tx = t & 31;
    const int ty = t >> 5;

    const float* p0 = part + (size_t)blockIdx.x * 4 * (KK * 128);

    float val[8][4];
#pragma unroll
    for (int i = 0; i < 8; ++i) {
        int k = ty * 8 + i;
        float4 s = make_float4(0.f, 0.f, 0.f, 0.f);
#pragma unroll
        for (int nc = 0; nc < 4; ++nc) {
            float4 v = *(const float4*)(p0 + (size_t)nc * (KK * 128) +
                                        (size_t)k * 128 + tx * 4);
            s.x += v.x; s.y += v.y; s.z += v.z; s.w += v.w;
        }
        float asv = a_sum[b * KK + k];
        float4 cv = *(const float4*)(c2 + (size_t)k * DD + d0 + tx * 4);
        val[i][0] = s.x - asv * cv.x;
        val[i][1] = s.y - asv * cv.y;
        val[i][2] = s.z - asv * cv.z;
        val[i][3] = s.w - asv * cv.w;
    }
    float p[4] = {0.f, 0.f, 0.f, 0.f};
#pragma unroll
    for (int i = 0; i < 8; ++i)
#pragma unroll
        for (int j = 0; j < 4; ++j) p[j] += val[i][j] * val[i][j];
    *(float4*)&red[ty][tx * 4] = make_float4(p[0], p[1], p[2], p[3]);
    __syncthreads();
    if (t < 128) {
        float s = 0.f;
#pragma unroll
        for (int g = 0; g < 8; ++g) s += red[g][t];
        float scale = 1.f / fmaxf(sqrtf(s), 1e-12f);
        sc[t] = scale;
        red[0][t] = s * scale * scale;
    }
    __syncthreads();
    if (t == 0) {
        float s = 0.f;
        for (int d = 0; d < 128; ++d) s += red[0][d];
        gsum_part[blockIdx.x] = s;
    }
#pragma unroll
    for (int i = 0; i < 8; ++i)
#pragma unroll
        for (int j = 0; j < 4; ++j)
            ot[tx * 4 + j][ty * 8 + i] = val[i][j] * sc[tx * 4 + j];
    __syncthreads();
    const size_t obase = (size_t)b * (DD * KK) + (size_t)d0 * KK;
#pragma unroll
    for (int i = 0; i < 32; ++i) {
        int f = t + i * 256;
        out[obase + f] = ot[f >> 6][f & 63];
    }
}

// ---------------------------------------------------------------------------
// K3: global L2 normalization per b
// ---------------------------------------------------------------------------
__global__ __launch_bounds__(256) void k_scale(
    float* __restrict__ out, const float* __restrict__ gsum_part)
{
    int idx = blockIdx.x * 256 + threadIdx.x;
    size_t f = (size_t)idx * 4;
    int b = (int)(f >> 15);                     // D*K = 32768 per b
    float s = gsum_part[b * 4 + 0] + gsum_part[b * 4 + 1] +
              gsum_part[b * 4 + 2] + gsum_part[b * 4 + 3];
    float scale = 1.f / fmaxf(sqrtf(s), 1e-12f);
    float4 v = *(float4*)(out + f);
    v.x *= scale; v.y *= scale; v.z *= scale; v.w *= scale;
    *(float4*)(out + f) = v;
}

extern "C" void kernel_launch(void* const* d_in, const int* in_sizes, int n_in,
                              void* d_out, int out_size, void* d_ws, size_t ws_size,
                              hipStream_t stream)
{
    const float* x        = (const float*)d_in[0];
    const float* clusters = (const float*)d_in[1];
    const float* rmean    = (const float*)d_in[2];
    const float* rvar     = (const float*)d_in[3];
    const float* c2       = (const float*)d_in[4];
    float* out = (float*)d_out;

    // workspace (floats): assign | asum_part | a_sum | gsum_part | part
    // bfrag (160KB) ALIASES part: k_prep writes it, k_assign reads it,
    // k_vlad_part overwrites it later (stream-ordered, deterministic).
    float* assign    = (float*)d_ws;                         // 4194304
    float* asum_part = assign + (size_t)BB * NN * KK;        // 1024*64
    float* a_sum     = asum_part + (size_t)1024 * KK;        // 4096
    float* gsum_part = a_sum + (size_t)BB * KK;              // 256
    float* part      = gsum_part + 256;                      // 1024*8192
    unsigned int* bfrag = (unsigned int*)part;               // 40960 dwords

    k_prep<<<160, 256, 0, stream>>>(clusters, bfrag);
    k_assign_mfma<<<1024, 256, 0, stream>>>(x, bfrag, rmean, rvar, assign, asum_part);
    k_asum_reduce<<<16, 256, 0, stream>>>(asum_part, a_sum);
    k_vlad_part<<<1024, 256, 0, stream>>>(x, assign, part);
    k_vlad_fin<<<256, 256, 0, stream>>>(part, a_sum, c2, out, gsum_part);
    k_scale<<<2048, 256, 0, stream>>>(out, gsum_part);
}

// Round 7
// 83.975 us; speedup vs baseline: 1.3503x; 1.3503x over previous
//
#include <hip/hip_runtime.h>
#include <math.h>

// NetVLAD: B=64, N=1024, D=512, K=64, G=16 (C=80)
#define BB 64
#define NN 1024
#define DD 512
#define KK 64
#define CC 80

typedef __attribute__((ext_vector_type(8))) short short8;  // 8 bf16 (4 VGPRs)
typedef __attribute__((ext_vector_type(4))) float f32x4;   // MFMA accumulator

union U16x8 { uint4 u; short8 s; };

// barrier that does NOT drain vmcnt: VGPR global loads stay in flight.
// LDS ops must complete (lgkmcnt) for cross-wave visibility.
__device__ __forceinline__ void bar() {
    asm volatile("s_waitcnt lgkmcnt(0)" ::: "memory");
    __builtin_amdgcn_s_barrier();
    __builtin_amdgcn_sched_barrier(0);
}

// Split fp32 -> bf16 hi (truncated) + bf16 lo. Used in assign main loop.
__device__ __forceinline__ void cvt_hilo8(const float* f, short8& hi, short8& lo) {
#pragma unroll
    for (int j = 0; j < 8; ++j) {
        unsigned u = __float_as_uint(f[j]);
        unsigned uh = u & 0xFFFF0000u;
        float fl = f[j] - __uint_as_float(uh);
        hi[j] = (short)(uh >> 16);
        lo[j] = (short)(__float_as_uint(fl) >> 16);
    }
}

// RTN split: returns (hi_bits) | (lo_bits<<16); hi = RTN-bf16(f), lo = RTN-bf16(f-hi).
__device__ __forceinline__ unsigned bf16_rtn(float f) {
    unsigned u = __float_as_uint(f);
    return (u + 0x7FFFu + ((u >> 16) & 1u)) >> 16;
}
__device__ __forceinline__ unsigned split_pack(float f) {
    unsigned hb = bf16_rtn(f);
    float hf = __uint_as_float(hb << 16);
    unsigned lb = bf16_rtn(f - hf);
    return hb | (lb << 16);
}

// ---------------------------------------------------------------------------
// K0: pre-swizzle clusters into per-lane MFMA B-frag layout (bf16 hi/lo).
// ---------------------------------------------------------------------------
__global__ __launch_bounds__(256) void k_prep(
    const float* __restrict__ clusters, unsigned int* __restrict__ bfrag)
{
    int i = blockIdx.x * 256 + threadIdx.x;
    if (i >= 16 * 10 * 64 * 4) return;
    int dw = i & 3;
    int l = (i >> 2) & 63;
    int rest = i >> 8;           // 0..159
    int q = rest % 10;
    int ks = rest / 10;
    int tile = q >> 1, part = q & 1;
    int c = tile * 16 + (l & 15);
    int dbase = ks * 32 + (l >> 4) * 8 + dw * 2;
    unsigned outw = 0;
#pragma unroll
    for (int e = 0; e < 2; ++e) {
        float v = clusters[(size_t)(dbase + e) * CC + c];
        unsigned u = __float_as_uint(v);
        unsigned uh = u & 0xFFFF0000u;
        unsigned h;
        if (part == 0) h = uh >> 16;
        else {
            float fl = v - __uint_as_float(uh);
            h = __float_as_uint(fl) >> 16;
        }
        outw |= h << (16 * e);
    }
    bfrag[i] = outw;
}

// ---------------------------------------------------------------------------
// K1: scores GEMM (split-bf16 MFMA) + BN + softmax; emits afrag (the A-frag
// layout vlad consumes, bf16 hi/lo RTN) + per-block column sums.
// Pipeline per half-iter: COMPUTE(cur) ; LOAD(k+2) ; STAGE(k+1) ; bar.
// LOAD before STAGE => counted vmcnt (newer set stays in flight across bar).
// xs3 padded [4][65][3] so A-frag ds_read_b128 is ~2-way (was 8-way).
// ---------------------------------------------------------------------------
__global__ __launch_bounds__(256, 3) void k_assign_mfma(
    const float* __restrict__ x,           // (B*N, D)
    const unsigned int* __restrict__ bfrag,
    const float* __restrict__ rmean,
    const float* __restrict__ rvar,
    uint4* __restrict__ afrag,             // (BN/32, 4kt, 2part, 64lane) uint4
    float* __restrict__ asum_part)         // (1024, K)
{
    union SmA {
        struct { float4 xs3[2][4][65][3]; uint4 bfu[2][640]; } g;  // 45.4KB
        float ss[64][68];                                          // 17.4KB
    };
    __shared__ SmA sm;
    __shared__ float colp[4][64];
    __shared__ float bnm[CC], bns[CC];

    const int t = threadIdx.x;
    const int w = t >> 6;       // wave 0..3
    const int l = t & 63;       // lane
    const int row0 = blockIdx.x * 64;

    if (t < CC) {
        bnm[t] = rmean[t];
        bns[t] = rsqrtf(rvar[t] + 1e-5f);
    }

    f32x4 acc[5];
#pragma unroll
    for (int nt = 0; nt < 5; ++nt)
#pragma unroll
        for (int r = 0; r < 4; ++r) acc[nt][r] = 0.f;

    // staging roles: rows rA, rA+32 at d-quad dq
    const int rA = t >> 3;        // 0..31
    const int dq = t & 7;         // 0..7
    const int g = dq >> 1, half = dq & 1;
    const float* xg = x + (size_t)(row0 + rA) * DD + dq * 4;
    const uint4* gb0 = (const uint4*)bfrag;

    // fragment-read roles
    const int frow = w * 16 + (l & 15);
    const int fg = l >> 4;

    float4 pvA0, pvA1, pvB0, pvB1;
    uint4 pbA0, pbA1, pbA2, pbB0, pbB1, pbB2;

#define LOAD_SET(S, ksv)                                            \
    do {                                                            \
        const float* xn = xg + (ksv) * 32;                          \
        pv##S##0 = *(const float4*)(xn);                            \
        pv##S##1 = *(const float4*)(xn + 32 * DD);                  \
        const uint4* gb = gb0 + (size_t)(ksv) * 640;                \
        pb##S##0 = gb[t];                                           \
        pb##S##1 = gb[t + 256];                                     \
        if (t < 128) pb##S##2 = gb[t + 512];                        \
    } while (0)

#define STAGE_SET(S, bi)                                            \
    do {                                                            \
        sm.g.xs3[bi][g][rA][half] = pv##S##0;                       \
        sm.g.xs3[bi][g][rA + 32][half] = pv##S##1;                  \
        sm.g.bfu[bi][t] = pb##S##0;                                 \
        sm.g.bfu[bi][t + 256] = pb##S##1;                           \
        if (t < 128) sm.g.bfu[bi][t + 512] = pb##S##2;              \
    } while (0)

#define COMPUTE(bi)                                                 \
    do {                                                            \
        float4 a0 = sm.g.xs3[bi][fg][frow][0];                      \
        float4 a1 = sm.g.xs3[bi][fg][frow][1];                      \
        float ftmp[8] = {a0.x, a0.y, a0.z, a0.w,                    \
                         a1.x, a1.y, a1.z, a1.w};                   \
        short8 ah, al;                                              \
        cvt_hilo8(ftmp, ah, al);                                    \
        _Pragma("unroll")                                           \
        for (int nt = 0; nt < 5; ++nt) {                            \
            U16x8 uh, ul;                                           \
            uh.u = sm.g.bfu[bi][(nt * 2 + 0) * 64 + l];             \
            ul.u = sm.g.bfu[bi][(nt * 2 + 1) * 64 + l];             \
            acc[nt] = __builtin_amdgcn_mfma_f32_16x16x32_bf16(      \
                ah, uh.s, acc[nt], 0, 0, 0);                        \
            acc[nt] = __builtin_amdgcn_mfma_f32_16x16x32_bf16(      \
                al, uh.s, acc[nt], 0, 0, 0);                        \
            acc[nt] = __builtin_amdgcn_mfma_f32_16x16x32_bf16(      \
                ah, ul.s, acc[nt], 0, 0, 0);                        \
        }                                                           \
    } while (0)

    // prologue
    LOAD_SET(A, 0);
    STAGE_SET(A, 0);
    LOAD_SET(B, 1);
    bar();

    for (int ks2 = 0; ks2 < 8; ++ks2) {
        const int ks = ks2 * 2;
        COMPUTE(0);
        if (ks2 < 7) LOAD_SET(A, ks + 2);   // newer set in flight...
        STAGE_SET(B, 1);                    // ...so this drain is COUNTED
        bar();
        COMPUTE(1);
        if (ks2 < 7) {
            LOAD_SET(B, ks + 3);
            STAGE_SET(A, 0);
            bar();
        }
    }
    __syncthreads();   // main-loop LDS dead; epilogue reuses as ss

    // BN + softmax per row, fully in-register
    float a[4][4];
#pragma unroll
    for (int r = 0; r < 4; ++r) {
        float sc[5];
#pragma unroll
        for (int nt = 0; nt < 5; ++nt) {
            int c = nt * 16 + (l & 15);
            sc[nt] = (acc[nt][r] - bnm[c]) * bns[c];
        }
        float m = sc[0];
#pragma unroll
        for (int nt = 1; nt < 5; ++nt) m = fmaxf(m, sc[nt]);
        m = fmaxf(m, __shfl_xor(m, 1));
        m = fmaxf(m, __shfl_xor(m, 2));
        m = fmaxf(m, __shfl_xor(m, 4));
        m = fmaxf(m, __shfl_xor(m, 8));
        float p[5], sum = 0.f;
#pragma unroll
        for (int nt = 0; nt < 5; ++nt) { p[nt] = __expf(sc[nt] - m); sum += p[nt]; }
        sum += __shfl_xor(sum, 1);
        sum += __shfl_xor(sum, 2);
        sum += __shfl_xor(sum, 4);
        sum += __shfl_xor(sum, 8);
        float rinv = 1.f / sum;
#pragma unroll
        for (int nt = 0; nt < 4; ++nt) a[nt][r] = p[nt] * rinv;
    }

    // stage a-values (n_local, k) + column sums
#pragma unroll
    for (int nt = 0; nt < 4; ++nt) {
#pragma unroll
        for (int r = 0; r < 4; ++r)
            sm.ss[w * 16 + (l >> 4) * 4 + r][nt * 16 + (l & 15)] = a[nt][r];
        float cs = a[nt][0] + a[nt][1] + a[nt][2] + a[nt][3];
        cs += __shfl_xor(cs, 16);
        cs += __shfl_xor(cs, 32);
        if (l < 16) colp[w][nt * 16 + l] = cs;
    }
    __syncthreads();

    // emit afrag: combo cm = c*8 + kt*2 + part; lane l: k=kt*16+(l&15),
    // n = c*32 + (l>>4)*8 + j. RTN hi/lo split.
#pragma unroll
    for (int i = 0; i < 4; ++i) {
        int cm = w * 4 + i;
        int c = cm >> 3, kt = (cm >> 1) & 3, part = cm & 1;
        int k = kt * 16 + (l & 15);
        int nb = c * 32 + (l >> 4) * 8;
        unsigned ow[4];
#pragma unroll
        for (int j2 = 0; j2 < 4; ++j2) {
            unsigned w0 = split_pack(sm.ss[nb + 2 * j2][k]);
            unsigned w1 = split_pack(sm.ss[nb + 2 * j2 + 1][k]);
            ow[j2] = (part == 0) ? ((w0 & 0xFFFFu) | (w1 << 16))
                                 : ((w0 >> 16) | (w1 & 0xFFFF0000u));
        }
        int chunkg = blockIdx.x * 2 + c;
        afrag[(size_t)(chunkg * 8 + kt * 2 + part) * 64 + l] =
            make_uint4(ow[0], ow[1], ow[2], ow[3]);
    }

    if (t < 64) {
        asum_part[(size_t)blockIdx.x * KK + t] =
            colp[0][t] + colp[1][t] + colp[2][t] + colp[3][t];
    }
#undef LOAD_SET
#undef STAGE_SET
#undef COMPUTE
}

// ---------------------------------------------------------------------------
// K2: vlad partial GEMM via split-bf16 MFMA. Block=(b, dt 128-d, nc 256-n).
// A-frags direct from afrag (L2). B = x staged transposed+packed (hi|lo u32)
// into XOR-swizzled LDS: element (d,n) at xTp[d][n ^ (((d>>2)&3)*8)].
// Same LOAD-early / counted-vmcnt pipeline.
// Out per block: 64k x 128d partial -> part.
// ---------------------------------------------------------------------------
__global__ __launch_bounds__(256, 3) void k_vlad_mfma(
    const float* __restrict__ x,
    const uint4* __restrict__ afrag4,
    float* __restrict__ part)
{
    __shared__ unsigned xTp[128][40];   // 20KB

    const int t = threadIdx.x;
    const int w = t >> 6, l = t & 63;
    const int b  = blockIdx.x >> 4;
    const int dt = (blockIdx.x >> 2) & 3;
    const int nc = blockIdx.x & 3;
    const int d0 = dt * 128;

    const int sn = t >> 3;      // staging n 0..31
    const int sdq = t & 7;      // staging d-quad
    const size_t xrow0 = (size_t)(b * NN + nc * 256);
    const int chunk0 = b * 32 + nc * 8;

    const int fd = l & 15;      // frag d-within-tile
    const int fg = l >> 4;      // frag n-group
    const int cb = ((fg ^ (fd >> 2)) & 3) * 8;   // swizzled col block

    f32x4 acc[4][2];
#pragma unroll
    for (int kt = 0; kt < 4; ++kt)
#pragma unroll
        for (int dn = 0; dn < 2; ++dn)
#pragma unroll
            for (int r = 0; r < 4; ++r) acc[kt][dn][r] = 0.f;

    float4 pvA0, pvA1, pvA2, pvA3, pvB0, pvB1, pvB2, pvB3;

#define VLOAD(S, chv)                                               \
    do {                                                            \
        const float* xr = x + (xrow0 + (chv) * 32 + sn) * DD + d0;  \
        pv##S##0 = *(const float4*)(xr + (sdq +  0) * 4);           \
        pv##S##1 = *(const float4*)(xr + (sdq +  8) * 4);           \
        pv##S##2 = *(const float4*)(xr + (sdq + 16) * 4);           \
        pv##S##3 = *(const float4*)(xr + (sdq + 24) * 4);           \
    } while (0)

#define VSTAGE(S)                                                   \
    do {                                                            \
        float4 vv[4] = {pv##S##0, pv##S##1, pv##S##2, pv##S##3};    \
        _Pragma("unroll")                                           \
        for (int i_ = 0; i_ < 4; ++i_) {                            \
            int db = (sdq + 8 * i_) * 4;                            \
            float fv[4] = {vv[i_].x, vv[i_].y, vv[i_].z, vv[i_].w}; \
            _Pragma("unroll")                                       \
            for (int e = 0; e < 4; ++e) {                           \
                int d = db + e;                                     \
                xTp[d][sn ^ (((d >> 2) & 3) * 8)] = split_pack(fv[e]); \
            }                                                       \
        }                                                           \
    } while (0)

#define VCOMPUTE(chv)                                               \
    do {                                                            \
        const uint4* ap = afrag4 + (size_t)(chunk0 + (chv)) * 512 + l; \
        U16x8 af[4][2];                                             \
        _Pragma("unroll")                                           \
        for (int kt = 0; kt < 4; ++kt)                              \
            _Pragma("unroll")                                       \
            for (int p = 0; p < 2; ++p)                             \
                af[kt][p].u = ap[(kt * 2 + p) * 64];                \
        _Pragma("unroll")                                           \
        for (int dnl = 0; dnl < 2; ++dnl) {                         \
            int d = (w * 2 + dnl) * 16 + fd;                        \
            const unsigned* row = &xTp[d][cb];                      \
            uint4 u0 = *(const uint4*)(row);                        \
            uint4 u1 = *(const uint4*)(row + 4);                    \
            unsigned uu[8] = {u0.x, u0.y, u0.z, u0.w,               \
                              u1.x, u1.y, u1.z, u1.w};              \
            unsigned bhw[4], blw[4];                                \
            _Pragma("unroll")                                       \
            for (int j2 = 0; j2 < 4; ++j2) {                        \
                unsigned e0 = uu[2 * j2], e1 = uu[2 * j2 + 1];      \
                bhw[j2] = (e0 & 0xFFFFu) | (e1 << 16);              \
                blw[j2] = (e0 >> 16) | (e1 & 0xFFFF0000u);          \
            }                                                       \
            U16x8 bh, bl;                                           \
            bh.u = make_uint4(bhw[0], bhw[1], bhw[2], bhw[3]);      \
            bl.u = make_uint4(blw[0], blw[1], blw[2], blw[3]);      \
            _Pragma("unroll")                                       \
            for (int kt = 0; kt < 4; ++kt) {                        \
                acc[kt][dnl] = __builtin_amdgcn_mfma_f32_16x16x32_bf16( \
                    af[kt][0].s, bh.s, acc[kt][dnl], 0, 0, 0);      \
                acc[kt][dnl] = __builtin_amdgcn_mfma_f32_16x16x32_bf16( \
                    af[kt][1].s, bh.s, acc[kt][dnl], 0, 0, 0);      \
                acc[kt][dnl] = __builtin_amdgcn_mfma_f32_16x16x32_bf16( \
                    af[kt][0].s, bl.s, acc[kt][dnl], 0, 0, 0);      \
            }                                                       \
        }                                                           \
    } while (0)

    VLOAD(A, 0);
    VLOAD(B, 1);
    for (int c2 = 0; c2 < 4; ++c2) {
        const int ch = c2 * 2;
        bar();                      // prev readers done
        VSTAGE(A);                  // counted: B set newer, in flight
        bar();
        if (c2 < 3) VLOAD(A, ch + 2);
        VCOMPUTE(ch);
        bar();
        VSTAGE(B);
        bar();
        if (c2 < 3) VLOAD(B, ch + 3);
        VCOMPUTE(ch + 1);
    }

    // write partial: k = kt*16 + fg*4 + r ; d = (w*2+dnl)*16 + fd
    float* pp = part + (size_t)blockIdx.x * (KK * 128);
#pragma unroll
    for (int kt = 0; kt < 4; ++kt)
#pragma unroll
        for (int dnl = 0; dnl < 2; ++dnl)
#pragma unroll
            for (int r = 0; r < 4; ++r)
                pp[(size_t)(kt * 16 + fg * 4 + r) * 128 + (w * 2 + dnl) * 16 + fd] =
                    acc[kt][dnl][r];
#undef VLOAD
#undef VSTAGE
#undef VCOMPUTE
}

// ---------------------------------------------------------------------------
// K3: reduce 4 N-chunk partials + fold a_sum from asum_part, subtract
// a_sum*c2, intra-norm over k, coalesced write, global-sumsq partial.
// ---------------------------------------------------------------------------
__global__ __launch_bounds__(256) void k_vlad_fin(
    const float* __restrict__ part,      // (1024, 64*128)
    const float* __restrict__ asum_part, // (1024, K)
    const float* __restrict__ c2,        // (K, D)
    float* __restrict__ out,             // (B, D*K)
    float* __restrict__ gsum_part)       // (B*4)
{
    __shared__ float red[8][128];
    __shared__ float sc[128];
    __shared__ float ot[128][65];
    __shared__ float asv[64];

    const int t = threadIdx.x;
    const int b = blockIdx.x >> 2;
    const int dt = blockIdx.x & 3;
    const int d0 = dt * 128;

    const int tx = t & 31;
    const int ty = t >> 5;

    if (t < 64) {
        float s = 0.f;
#pragma unroll
        for (int tile = 0; tile < 16; ++tile)
            s += asum_part[(size_t)(b * 16 + tile) * KK + t];
        asv[t] = s;
    }
    __syncthreads();

    const float* p0 = part + (size_t)blockIdx.x * 4 * (KK * 128);

    float val[8][4];
#pragma unroll
    for (int i = 0; i < 8; ++i) {
        int k = ty * 8 + i;
        float4 s = make_float4(0.f, 0.f, 0.f, 0.f);
#pragma unroll
        for (int nc = 0; nc < 4; ++nc) {
            float4 v = *(const float4*)(p0 + (size_t)nc * (KK * 128) +
                                        (size_t)k * 128 + tx * 4);
            s.x += v.x; s.y += v.y; s.z += v.z; s.w += v.w;
        }
        float asvk = asv[k];
        float4 cv = *(const float4*)(c2 + (size_t)k * DD + d0 + tx * 4);
        val[i][0] = s.x - asvk * cv.x;
        val[i][1] = s.y - asvk * cv.y;
        val[i][2] = s.z - asvk * cv.z;
        val[i][3] = s.w - asvk * cv.w;
    }
    float p[4] = {0.f, 0.f, 0.f, 0.f};
#pragma unroll
    for (int i = 0; i < 8; ++i)
#pragma unroll
        for (int j = 0; j < 4; ++j) p[j] += val[i][j] * val[i][j];
    *(float4*)&red[ty][tx * 4] = make_float4(p[0], p[1], p[2], p[3]);
    __syncthreads();
    if (t < 128) {
        float s = 0.f;
#pragma unroll
        for (int g = 0; g < 8; ++g) s += red[g][t];
        float scale = 1.f / fmaxf(sqrtf(s), 1e-12f);
        sc[t] = scale;
        red[0][t] = s * scale * scale;
    }
    __syncthreads();
    if (t == 0) {
        float s = 0.f;
        for (int d = 0; d < 128; ++d) s += red[0][d];
        gsum_part[blockIdx.x] = s;
    }
#pragma unroll
    for (int i = 0; i < 8; ++i)
#pragma unroll
        for (int j = 0; j < 4; ++j)
            ot[tx * 4 + j][ty * 8 + i] = val[i][j] * sc[tx * 4 + j];
    __syncthreads();
    const size_t obase = (size_t)b * (DD * KK) + (size_t)d0 * KK;
#pragma unroll
    for (int i = 0; i < 32; ++i) {
        int f = t + i * 256;
        out[obase + f] = ot[f >> 6][f & 63];
    }
}

// ---------------------------------------------------------------------------
// K4: global L2 normalization per b
// ---------------------------------------------------------------------------
__global__ __launch_bounds__(256) void k_scale(
    float* __restrict__ out, const float* __restrict__ gsum_part)
{
    int idx = blockIdx.x * 256 + threadIdx.x;
    size_t f = (size_t)idx * 4;
    int b = (int)(f >> 15);                     // D*K = 32768 per b
    float s = gsum_part[b * 4 + 0] + gsum_part[b * 4 + 1] +
              gsum_part[b * 4 + 2] + gsum_part[b * 4 + 3];
    float scale = 1.f / fmaxf(sqrtf(s), 1e-12f);
    float4 v = *(float4*)(out + f);
    v.x *= scale; v.y *= scale; v.z *= scale; v.w *= scale;
    *(float4*)(out + f) = v;
}

extern "C" void kernel_launch(void* const* d_in, const int* in_sizes, int n_in,
                              void* d_out, int out_size, void* d_ws, size_t ws_size,
                              hipStream_t stream)
{
    const float* x        = (const float*)d_in[0];
    const float* clusters = (const float*)d_in[1];
    const float* rmean    = (const float*)d_in[2];
    const float* rvar     = (const float*)d_in[3];
    const float* c2       = (const float*)d_in[4];
    float* out = (float*)d_out;

    // workspace: afrag (16MB) | asum_part | gsum_part | part (32MB)
    // bfrag (160KB) aliases part: k_prep writes, k_assign reads,
    // k_vlad_mfma overwrites later (stream-ordered, deterministic).
    unsigned* afrag   = (unsigned*)d_ws;                     // 4,194,304 u32
    float* asum_part  = (float*)d_ws + 4194304;              // 65536
    float* gsum_part  = asum_part + 65536;                   // 256
    float* part       = gsum_part + 256;                     // 8,388,608
    unsigned* bfrag   = (unsigned*)part;                     // 40960 dwords

    k_prep<<<160, 256, 0, stream>>>(clusters, bfrag);
    k_assign_mfma<<<1024, 256, 0, stream>>>(x, bfrag, rmean, rvar,
                                            (uint4*)afrag, asum_part);
    k_vlad_mfma<<<1024, 256, 0, stream>>>(x, (const uint4*)afrag, part);
    k_vlad_fin<<<256, 256, 0, stream>>>(part, asum_part, c2, out, gsum_part);
    k_scale<<<2048, 256, 0, stream>>>(out, gsum_part);
}

// Round 9
// 77.281 us; speedup vs baseline: 1.4672x; 1.0866x over previous
//
#include <hip/hip_runtime.h>
#include <math.h>

// NetVLAD: B=64, N=1024, D=512, K=64, G=16 (C=80)
#define BB 64
#define NN 1024
#define DD 512
#define KK 64
#define CC 80

typedef __attribute__((ext_vector_type(8))) short short8;  // 8 bf16 (4 VGPRs)
typedef __attribute__((ext_vector_type(4))) float f32x4;   // MFMA accumulator

union U16x8 { uint4 u; short8 s; };

// barrier that does NOT drain vmcnt: VGPR global loads stay in flight.
__device__ __forceinline__ void bar() {
    asm volatile("s_waitcnt lgkmcnt(0)" ::: "memory");
    __builtin_amdgcn_s_barrier();
    __builtin_amdgcn_sched_barrier(0);
}

// Split fp32 -> bf16 hi (truncated) + bf16 lo. Used in assign main loop.
__device__ __forceinline__ void cvt_hilo8(const float* f, short8& hi, short8& lo) {
#pragma unroll
    for (int j = 0; j < 8; ++j) {
        unsigned u = __float_as_uint(f[j]);
        unsigned uh = u & 0xFFFF0000u;
        float fl = f[j] - __uint_as_float(uh);
        hi[j] = (short)(uh >> 16);
        lo[j] = (short)(__float_as_uint(fl) >> 16);
    }
}

// RTN split: (hi_bits) | (lo_bits<<16); hi = RTN-bf16(f), lo = RTN-bf16(f-hi).
__device__ __forceinline__ unsigned bf16_rtn(float f) {
    unsigned u = __float_as_uint(f);
    return (u + 0x7FFFu + ((u >> 16) & 1u)) >> 16;
}
__device__ __forceinline__ unsigned split_pack(float f) {
    unsigned hb = bf16_rtn(f);
    float hf = __uint_as_float(hb << 16);
    unsigned lb = bf16_rtn(f - hf);
    return hb | (lb << 16);
}

// ---------------------------------------------------------------------------
// K0: pre-swizzle clusters into per-lane MFMA B-frag layout (bf16 hi/lo).
// ---------------------------------------------------------------------------
__global__ __launch_bounds__(256) void k_prep(
    const float* __restrict__ clusters, unsigned int* __restrict__ bfrag)
{
    int i = blockIdx.x * 256 + threadIdx.x;
    if (i >= 16 * 10 * 64 * 4) return;
    int dw = i & 3;
    int l = (i >> 2) & 63;
    int rest = i >> 8;           // 0..159
    int q = rest % 10;
    int ks = rest / 10;
    int tile = q >> 1, part = q & 1;
    int c = tile * 16 + (l & 15);
    int dbase = ks * 32 + (l >> 4) * 8 + dw * 2;
    unsigned outw = 0;
#pragma unroll
    for (int e = 0; e < 2; ++e) {
        float v = clusters[(size_t)(dbase + e) * CC + c];
        unsigned u = __float_as_uint(v);
        unsigned uh = u & 0xFFFF0000u;
        unsigned h;
        if (part == 0) h = uh >> 16;
        else {
            float fl = v - __uint_as_float(uh);
            h = __float_as_uint(fl) >> 16;
        }
        outw |= h << (16 * e);
    }
    bfrag[i] = outw;
}

// ---------------------------------------------------------------------------
// K1: scores GEMM (split-bf16 MFMA) + BN + softmax; emits afrag + asum_part.
// 4-deep register prefetch (sets A..D): each load gets ~3 iterations of
// cover before its STAGE drains it (counted vmcnt: newer sets in flight).
// ---------------------------------------------------------------------------
__global__ __launch_bounds__(256, 2) void k_assign_mfma(
    const float* __restrict__ x,           // (B*N, D)
    const unsigned int* __restrict__ bfrag,
    const float* __restrict__ rmean,
    const float* __restrict__ rvar,
    uint4* __restrict__ afrag,             // (BN/32, 4kt, 2part, 64lane) uint4
    float* __restrict__ asum_part)         // (1024, K)
{
    union SmA {
        struct { float4 xs3[2][4][65][3]; uint4 bfu[2][640]; } g;  // 45.4KB
        float ss[64][68];                                          // 17.4KB
    };
    __shared__ SmA sm;
    __shared__ float colp[4][64];
    __shared__ float bnm[CC], bns[CC];

    const int t = threadIdx.x;
    const int w = t >> 6;       // wave 0..3
    const int l = t & 63;       // lane
    const int row0 = blockIdx.x * 64;

    if (t < CC) {
        bnm[t] = rmean[t];
        bns[t] = rsqrtf(rvar[t] + 1e-5f);
    }

    f32x4 acc[5];
#pragma unroll
    for (int nt = 0; nt < 5; ++nt)
#pragma unroll
        for (int r = 0; r < 4; ++r) acc[nt][r] = 0.f;

    // staging roles: rows rA, rA+32 at d-quad dq
    const int rA = t >> 3;        // 0..31
    const int dq = t & 7;         // 0..7
    const int g = dq >> 1, half = dq & 1;
    const float* xg = x + (size_t)(row0 + rA) * DD + dq * 4;
    const uint4* gb0 = (const uint4*)bfrag;

    // fragment-read roles
    const int frow = w * 16 + (l & 15);
    const int fg = l >> 4;

    float4 pvA0, pvA1, pvB0, pvB1, pvC0, pvC1, pvD0, pvD1;
    uint4 pbA0, pbA1, pbA2, pbB0, pbB1, pbB2;
    uint4 pbC0, pbC1, pbC2, pbD0, pbD1, pbD2;

#define LOAD_SET(S, ksv)                                            \
    do {                                                            \
        const float* xn = xg + (ksv) * 32;                          \
        pv##S##0 = *(const float4*)(xn);                            \
        pv##S##1 = *(const float4*)(xn + 32 * DD);                  \
        const uint4* gb = gb0 + (size_t)(ksv) * 640;                \
        pb##S##0 = gb[t];                                           \
        pb##S##1 = gb[t + 256];                                     \
        if (t < 128) pb##S##2 = gb[t + 512];                        \
    } while (0)

#define STAGE_SET(S, bi)                                            \
    do {                                                            \
        sm.g.xs3[bi][g][rA][half] = pv##S##0;                       \
        sm.g.xs3[bi][g][rA + 32][half] = pv##S##1;                  \
        sm.g.bfu[bi][t] = pb##S##0;                                 \
        sm.g.bfu[bi][t + 256] = pb##S##1;                           \
        if (t < 128) sm.g.bfu[bi][t + 512] = pb##S##2;              \
    } while (0)

#define COMPUTE(bi)                                                 \
    do {                                                            \
        float4 a0 = sm.g.xs3[bi][fg][frow][0];                      \
        float4 a1 = sm.g.xs3[bi][fg][frow][1];                      \
        float ftmp[8] = {a0.x, a0.y, a0.z, a0.w,                    \
                         a1.x, a1.y, a1.z, a1.w};                   \
        short8 ah, al;                                              \
        cvt_hilo8(ftmp, ah, al);                                    \
        _Pragma("unroll")                                           \
        for (int nt = 0; nt < 5; ++nt) {                            \
            U16x8 uh, ul;                                           \
            uh.u = sm.g.bfu[bi][(nt * 2 + 0) * 64 + l];             \
            ul.u = sm.g.bfu[bi][(nt * 2 + 1) * 64 + l];             \
            acc[nt] = __builtin_amdgcn_mfma_f32_16x16x32_bf16(      \
                ah, uh.s, acc[nt], 0, 0, 0);                        \
            acc[nt] = __builtin_amdgcn_mfma_f32_16x16x32_bf16(      \
                al, uh.s, acc[nt], 0, 0, 0);                        \
            acc[nt] = __builtin_amdgcn_mfma_f32_16x16x32_bf16(      \
                ah, ul.s, acc[nt], 0, 0, 0);                        \
        }                                                           \
    } while (0)

    // prologue: issue 4 chunks, stage chunk0 (wait is counted: B,C,D newer)
    LOAD_SET(A, 0);
    LOAD_SET(B, 1);
    LOAD_SET(C, 2);
    LOAD_SET(D, 3);
    STAGE_SET(A, 0);
    bar();

    for (int gq = 0; gq < 4; ++gq) {
        const int ks = gq * 4;
        COMPUTE(0);                              // chunk ks
        if (gq < 3) LOAD_SET(A, ks + 4);
        STAGE_SET(B, 1);
        bar();
        COMPUTE(1);                              // chunk ks+1
        if (gq < 3) LOAD_SET(B, ks + 5);
        STAGE_SET(C, 0);
        bar();
        COMPUTE(0);                              // chunk ks+2
        if (gq < 3) LOAD_SET(C, ks + 6);
        STAGE_SET(D, 1);
        bar();
        COMPUTE(1);                              // chunk ks+3
        if (gq < 3) {
            LOAD_SET(D, ks + 7);
            STAGE_SET(A, 0);
            bar();
        }
    }
    __syncthreads();   // main-loop LDS dead; epilogue reuses as ss

    // BN + softmax per row, fully in-register
    float a[4][4];
#pragma unroll
    for (int r = 0; r < 4; ++r) {
        float sc[5];
#pragma unroll
        for (int nt = 0; nt < 5; ++nt) {
            int c = nt * 16 + (l & 15);
            sc[nt] = (acc[nt][r] - bnm[c]) * bns[c];
        }
        float m = sc[0];
#pragma unroll
        for (int nt = 1; nt < 5; ++nt) m = fmaxf(m, sc[nt]);
        m = fmaxf(m, __shfl_xor(m, 1));
        m = fmaxf(m, __shfl_xor(m, 2));
        m = fmaxf(m, __shfl_xor(m, 4));
        m = fmaxf(m, __shfl_xor(m, 8));
        float p[5], sum = 0.f;
#pragma unroll
        for (int nt = 0; nt < 5; ++nt) { p[nt] = __expf(sc[nt] - m); sum += p[nt]; }
        sum += __shfl_xor(sum, 1);
        sum += __shfl_xor(sum, 2);
        sum += __shfl_xor(sum, 4);
        sum += __shfl_xor(sum, 8);
        float rinv = 1.f / sum;
#pragma unroll
        for (int nt = 0; nt < 4; ++nt) a[nt][r] = p[nt] * rinv;
    }

    // stage a-values (n_local, k) + column sums
#pragma unroll
    for (int nt = 0; nt < 4; ++nt) {
#pragma unroll
        for (int r = 0; r < 4; ++r)
            sm.ss[w * 16 + (l >> 4) * 4 + r][nt * 16 + (l & 15)] = a[nt][r];
        float cs = a[nt][0] + a[nt][1] + a[nt][2] + a[nt][3];
        cs += __shfl_xor(cs, 16);
        cs += __shfl_xor(cs, 32);
        if (l < 16) colp[w][nt * 16 + l] = cs;
    }
    __syncthreads();

    // emit afrag: combo cm = c*8 + kt*2 + part; lane l: k=kt*16+(l&15),
    // n = c*32 + (l>>4)*8 + j. RTN hi/lo split.
#pragma unroll
    for (int i = 0; i < 4; ++i) {
        int cm = w * 4 + i;
        int c = cm >> 3, kt = (cm >> 1) & 3, part = cm & 1;
        int k = kt * 16 + (l & 15);
        int nb = c * 32 + (l >> 4) * 8;
        unsigned ow[4];
#pragma unroll
        for (int j2 = 0; j2 < 4; ++j2) {
            unsigned w0 = split_pack(sm.ss[nb + 2 * j2][k]);
            unsigned w1 = split_pack(sm.ss[nb + 2 * j2 + 1][k]);
            ow[j2] = (part == 0) ? ((w0 & 0xFFFFu) | (w1 << 16))
                                 : ((w0 >> 16) | (w1 & 0xFFFF0000u));
        }
        int chunkg = blockIdx.x * 2 + c;
        afrag[(size_t)(chunkg * 8 + kt * 2 + part) * 64 + l] =
            make_uint4(ow[0], ow[1], ow[2], ow[3]);
    }

    if (t < 64) {
        asum_part[(size_t)blockIdx.x * KK + t] =
            colp[0][t] + colp[1][t] + colp[2][t] + colp[3][t];
    }
#undef LOAD_SET
#undef STAGE_SET
#undef COMPUTE
}

// ---------------------------------------------------------------------------
// K2: FUSED vlad GEMM + epilogue. Block = (b, dt): full N-sum in-block
// (no part round-trip). 512 threads, 8 waves; wave w owns d-tile w*16..+15.
// afrag staged in LDS (kills the 8x-redundant L2 reads); x staged
// transposed+packed (hi|lo u32) with swizzle s(d)=((d>>2)^(d>>5))&3 and
// row stride 36 u32 (pad: read banks spread by dl*4; 144B keeps uint4 align).
// Epilogue: asum fold + c2 subtract + intra-norm over k + coalesced write.
// ---------------------------------------------------------------------------
__global__ __launch_bounds__(512, 2) void k_vlad_fused(
    const float* __restrict__ x,
    const uint4* __restrict__ afrag4,
    const float* __restrict__ asum_part,   // (1024, K)
    const float* __restrict__ c2,          // (K, D)
    float* __restrict__ out,               // (B, D*K)
    float* __restrict__ gsum_part)         // (B*4)
{
    union Sm {
        struct { unsigned xTp[2][128][36]; uint4 afu[2][512]; } m;  // 52KB
        float ot[128][68];                                          // 34.8KB
    };
    __shared__ Sm sm;
    __shared__ float asv[64];
    __shared__ float gw[8];

    const int t = threadIdx.x;
    const int w = t >> 6, l = t & 63;
    const int b  = blockIdx.x >> 2;
    const int dt = blockIdx.x & 3;
    const int d0 = dt * 128;

    // a_sum fold (independent of the main loop)
    if (t < 64) {
        float s = 0.f;
#pragma unroll
        for (int tile = 0; tile < 16; ++tile)
            s += asum_part[(size_t)(b * 16 + tile) * KK + t];
        asv[t] = s;
    }

    const int sn = t >> 4;      // staging n 0..31
    const int sdq = t & 15;     // staging d-octet 0..15
    const size_t xrow0 = (size_t)b * NN;
    const int chunk0 = b * 32;

    const int fd = l & 15;
    const int fg = l >> 4;
    const int dl = w * 16 + fd;                       // local d 0..127
    const int cb = ((fg ^ (dl >> 2) ^ (dl >> 5)) & 3) * 8;

    f32x4 acc[4];
#pragma unroll
    for (int kt = 0; kt < 4; ++kt)
#pragma unroll
        for (int r = 0; r < 4; ++r) acc[kt][r] = 0.f;

    float4 pxA0, pxA1, pxB0, pxB1;
    uint4 paA, paB;

#define VLOAD(S, chv)                                               \
    do {                                                            \
        const float* xr = x + (xrow0 + (chv) * 32 + sn) * DD +      \
                          d0 + sdq * 8;                             \
        px##S##0 = *(const float4*)(xr);                            \
        px##S##1 = *(const float4*)(xr + 4);                        \
        pa##S = afrag4[(size_t)(chunk0 + (chv)) * 512 + t];         \
    } while (0)

#define VSTAGE(S, bi)                                               \
    do {                                                            \
        float4 v0_ = px##S##0;                                      \
        float4 v1_ = px##S##1;                                      \
        float fv[8] = {v0_.x, v0_.y, v0_.z, v0_.w,                  \
                       v1_.x, v1_.y, v1_.z, v1_.w};                 \
        _Pragma("unroll")                                           \
        for (int e = 0; e < 8; ++e) {                               \
            int d = sdq * 8 + e;                                    \
            int s_ = ((d >> 2) ^ (d >> 5)) & 3;                     \
            sm.m.xTp[bi][d][sn ^ (s_ * 8)] = split_pack(fv[e]);     \
        }                                                           \
        sm.m.afu[bi][t] = pa##S;                                    \
    } while (0)

#define VCOMP(bi)                                                   \
    do {                                                            \
        U16x8 af[4][2];                                             \
        _Pragma("unroll")                                           \
        for (int kt = 0; kt < 4; ++kt) {                            \
            af[kt][0].u = sm.m.afu[bi][(kt * 2 + 0) * 64 + l];      \
            af[kt][1].u = sm.m.afu[bi][(kt * 2 + 1) * 64 + l];      \
        }                                                           \
        const unsigned* row = &sm.m.xTp[bi][dl][cb];                \
        uint4 u0 = *(const uint4*)(row);                            \
        uint4 u1 = *(const uint4*)(row + 4);                        \
        unsigned uu[8] = {u0.x, u0.y, u0.z, u0.w,                   \
                          u1.x, u1.y, u1.z, u1.w};                  \
        unsigned bhw[4], blw[4];                                    \
        _Pragma("unroll")                                           \
        for (int j2 = 0; j2 < 4; ++j2) {                            \
            unsigned e0 = uu[2 * j2], e1 = uu[2 * j2 + 1];          \
            bhw[j2] = (e0 & 0xFFFFu) | (e1 << 16);                  \
            blw[j2] = (e0 >> 16) | (e1 & 0xFFFF0000u);              \
        }                                                           \
        U16x8 bh, bl;                                               \
        bh.u = make_uint4(bhw[0], bhw[1], bhw[2], bhw[3]);          \
        bl.u = make_uint4(blw[0], blw[1], blw[2], blw[3]);          \
        _Pragma("unroll")                                           \
        for (int kt = 0; kt < 4; ++kt) {                            \
            acc[kt] = __builtin_amdgcn_mfma_f32_16x16x32_bf16(      \
                af[kt][0].s, bh.s, acc[kt], 0, 0, 0);               \
            acc[kt] = __builtin_amdgcn_mfma_f32_16x16x32_bf16(      \
                af[kt][1].s, bh.s, acc[kt], 0, 0, 0);               \
            acc[kt] = __builtin_amdgcn_mfma_f32_16x16x32_bf16(      \
                af[kt][0].s, bl.s, acc[kt], 0, 0, 0);               \
        }                                                           \
    } while (0)

    VLOAD(A, 0);
    VLOAD(B, 1);
    VSTAGE(A, 0);       // counted: B newer, stays in flight
    bar();

    for (int i = 0; i < 16; ++i) {
        VCOMP(0);                               // chunk 2i
        if (i < 15) VLOAD(A, 2 * i + 2);
        VSTAGE(B, 1);
        bar();
        VCOMP(1);                               // chunk 2i+1
        if (i < 15) {
            VLOAD(B, 2 * i + 3);
            VSTAGE(A, 0);
            bar();
        }
    }
    __syncthreads();    // main-loop LDS dead; epilogue reuses as ot

    // epilogue: subtract a_sum*c2, intra-norm over k (in-wave), gsum partial
    const int dgl = d0 + dl;
    float val[4][4];
#pragma unroll
    for (int kt = 0; kt < 4; ++kt)
#pragma unroll
        for (int r = 0; r < 4; ++r) {
            int k = kt * 16 + fg * 4 + r;
            val[kt][r] = acc[kt][r] - asv[k] * c2[(size_t)k * DD + dgl];
        }
    float ssd = 0.f;
#pragma unroll
    for (int kt = 0; kt < 4; ++kt)
#pragma unroll
        for (int r = 0; r < 4; ++r) ssd += val[kt][r] * val[kt][r];
    ssd += __shfl_xor(ssd, 16);
    ssd += __shfl_xor(ssd, 32);               // per-d sumsq over all 64 k
    float scale = 1.f / fmaxf(sqrtf(ssd), 1e-12f);

    float gl = ssd * scale * scale;           // per-d contribution (dup x4/fg)
    gl += __shfl_xor(gl, 1);
    gl += __shfl_xor(gl, 2);
    gl += __shfl_xor(gl, 4);
    gl += __shfl_xor(gl, 8);                  // sum over the wave's 16 d
    if (l == 0) gw[w] = gl;

    // stage normalized values (d-major) for coalesced write
#pragma unroll
    for (int kt = 0; kt < 4; ++kt)
#pragma unroll
        for (int r = 0; r < 4; ++r)
            sm.ot[dl][kt * 16 + fg * 4 + r] = val[kt][r] * scale;
    __syncthreads();
    if (t == 0) {
        float s = 0.f;
#pragma unroll
        for (int i = 0; i < 8; ++i) s += gw[i];
        gsum_part[blockIdx.x] = s;
    }
    const size_t obase = (size_t)b * (DD * KK) + (size_t)d0 * KK;
#pragma unroll
    for (int c = 0; c < 4; ++c) {
        int flat = t * 16 + c * 4;
        float4 v = *(float4*)&sm.ot[flat >> 6][flat & 63];
        *(float4*)(out + obase + flat) = v;
    }
#undef VLOAD
#undef VSTAGE
#undef VCOMP
}

// ---------------------------------------------------------------------------
// K3: global L2 normalization per b
// ---------------------------------------------------------------------------
__global__ __launch_bounds__(256) void k_scale(
    float* __restrict__ out, const float* __restrict__ gsum_part)
{
    int idx = blockIdx.x * 256 + threadIdx.x;
    size_t f = (size_t)idx * 4;
    int b = (int)(f >> 15);                     // D*K = 32768 per b
    float s = gsum_part[b * 4 + 0] + gsum_part[b * 4 + 1] +
              gsum_part[b * 4 + 2] + gsum_part[b * 4 + 3];
    float scale = 1.f / fmaxf(sqrtf(s), 1e-12f);
    float4 v = *(float4*)(out + f);
    v.x *= scale; v.y *= scale; v.z *= scale; v.w *= scale;
    *(float4*)(out + f) = v;
}

extern "C" void kernel_launch(void* const* d_in, const int* in_sizes, int n_in,
                              void* d_out, int out_size, void* d_ws, size_t ws_size,
                              hipStream_t stream)
{
    const float* x        = (const float*)d_in[0];
    const float* clusters = (const float*)d_in[1];
    const float* rmean    = (const float*)d_in[2];
    const float* rvar     = (const float*)d_in[3];
    const float* c2       = (const float*)d_in[4];
    float* out = (float*)d_out;

    // workspace: afrag (16MB) | asum_part | gsum_part | bfrag (160KB)
    unsigned* afrag   = (unsigned*)d_ws;                     // 4,194,304 u32
    float* asum_part  = (float*)d_ws + 4194304;              // 65536
    float* gsum_part  = asum_part + 65536;                   // 256
    unsigned* bfrag   = (unsigned*)(gsum_part + 256);        // 40960 dwords

    k_prep<<<160, 256, 0, stream>>>(clusters, bfrag);
    k_assign_mfma<<<1024, 256, 0, stream>>>(x, bfrag, rmean, rvar,
                                            (uint4*)afrag, asum_part);
    k_vlad_fused<<<256, 512, 0, stream>>>(x, (const uint4*)afrag, asum_part,
                                          c2, out, gsum_part);
    k_scale<<<2048, 256, 0, stream>>>(out, gsum_part);
}